// Round 4
// baseline (449.910 us; speedup 1.0000x reference)
//
#include <hip/hip_runtime.h>

#define NN 100000
#define NE 1200000
#define DD 64
#define EPS 1e-5f

// ---------------- degree histogram, 4 edges/thread ----------------
__global__ __launch_bounds__(256) void k_deg(const int* __restrict__ dst,
                                             int* __restrict__ cnt, int nq) {
    int i = blockIdx.x * 256 + threadIdx.x;
    if (i < nq) {
        int4 d = ((const int4*)dst)[i];
        atomicAdd(&cnt[d.x], 1);
        atomicAdd(&cnt[d.y], 1);
        atomicAdd(&cnt[d.z], 1);
        atomicAdd(&cnt[d.w], 1);
    }
}

// cnt -> dinv = rsqrt(cnt+1), in place (int buffer reused as float)
__global__ __launch_bounds__(256) void k_dinv(int* __restrict__ c, int n) {
    int i = blockIdx.x * 256 + threadIdx.x;
    if (i < n) {
        float v = rsqrtf((float)c[i] + 1.0f);
        ((float*)c)[i] = v;
    }
}

// ---------------- hierarchical exclusive scan of counts -> offsets ----------------
__global__ __launch_bounds__(512) void k_scan1(const int* __restrict__ cnt,
                                               int* __restrict__ out,
                                               int* __restrict__ bsum, int n) {
    __shared__ int s[512];
    int t = threadIdx.x;
    int i = blockIdx.x * 512 + t;
    int v = (i < n) ? cnt[i] : 0;
    s[t] = v;
    __syncthreads();
    for (int off = 1; off < 512; off <<= 1) {
        int u = (t >= off) ? s[t - off] : 0;
        __syncthreads();
        s[t] += u;
        __syncthreads();
    }
    if (i < n) out[i] = s[t] - v;          // block-local exclusive
    if (t == 511) bsum[blockIdx.x] = s[511];
}

__global__ __launch_bounds__(256) void k_scan2(int* __restrict__ bsum, int nb) {
    __shared__ int s[256];
    int t = threadIdx.x;
    int v = (t < nb) ? bsum[t] : 0;
    s[t] = v;
    __syncthreads();
    for (int off = 1; off < 256; off <<= 1) {
        int u = (t >= off) ? s[t - off] : 0;
        __syncthreads();
        s[t] += u;
        __syncthreads();
    }
    if (t < nb) bsum[t] = s[t] - v;        // exclusive scan of block sums
}

__global__ __launch_bounds__(512) void k_scan3(int* __restrict__ out,
                                               const int* __restrict__ bsum,
                                               int n, int e) {
    int i = blockIdx.x * 512 + threadIdx.x;
    if (i < n) out[i] += bsum[blockIdx.x];
    if (i == 0) out[n] = e;                // total = E always
}

// ---------------- CSR fill (src-only, 4B records), 4 edges/thread ----------------
__global__ __launch_bounds__(256) void k_fill(const int* __restrict__ src,
                                              const int* __restrict__ dst,
                                              int* __restrict__ cursor,
                                              int* __restrict__ esrc, int nq) {
    int i = blockIdx.x * 256 + threadIdx.x;
    if (i < nq) {
        int4 s = ((const int4*)src)[i];
        int4 d = ((const int4*)dst)[i];
        int p0 = atomicAdd(&cursor[d.x], 1);
        int p1 = atomicAdd(&cursor[d.y], 1);
        int p2 = atomicAdd(&cursor[d.z], 1);
        int p3 = atomicAdd(&cursor[d.w], 1);
        esrc[p0] = s.x;
        esrc[p1] = s.y;
        esrc[p2] = s.z;
        esrc[p3] = s.w;
    }
}

// ---------------- GEMM: XW = X @ W, optionally fusing BN-affine+leaky on X ----------------
template <bool BN>
__global__ __launch_bounds__(256) void k_gemm(const float* __restrict__ X,
                                              const float* __restrict__ W,
                                              float* __restrict__ XW,
                                              const float* __restrict__ stats,
                                              const float* __restrict__ gamma,
                                              const float* __restrict__ beta) {
    __shared__ float xs[32][64];
    __shared__ float sc_s[64], sh_s[64];
    int col = threadIdx.x & 63;
    int rg  = threadIdx.x >> 6;            // 0..3
    int row0 = blockIdx.x * 32;

    if (BN) {
        if (threadIdx.x < 64) {
            const float inv_n = 1.0f / (float)NN;
            float mu  = stats[threadIdx.x] * inv_n;
            float var = stats[64 + threadIdx.x] * inv_n - mu * mu;
            float sc  = gamma[threadIdx.x] * rsqrtf(var + EPS);
            sc_s[threadIdx.x] = sc;
            sh_s[threadIdx.x] = beta[threadIdx.x] - sc * mu;
        }
        __syncthreads();
    }

    // W column in registers (reads coalesced across lanes, L2-hot across blocks)
    float w[64];
#pragma unroll
    for (int k = 0; k < 64; ++k) w[k] = W[k * 64 + col];

    // stage 32x64 x-tile (fully coalesced float4 loads), optional BN+leaky
    for (int i = threadIdx.x; i < 32 * 16; i += 256) {
        int r = i >> 4, c4 = i & 15;
        float4 v = ((const float4*)(X + (size_t)(row0 + r) * 64))[c4];
        if (BN) {
            float4 s4 = ((const float4*)sc_s)[c4];
            float4 h4 = ((const float4*)sh_s)[c4];
            v.x = s4.x * v.x + h4.x; v.x = fmaxf(v.x, 0.01f * v.x);
            v.y = s4.y * v.y + h4.y; v.y = fmaxf(v.y, 0.01f * v.y);
            v.z = s4.z * v.z + h4.z; v.z = fmaxf(v.z, 0.01f * v.z);
            v.w = s4.w * v.w + h4.w; v.w = fmaxf(v.w, 0.01f * v.w);
        }
        ((float4*)&xs[r][0])[c4] = v;
    }
    __syncthreads();

    float acc[8];
#pragma unroll
    for (int r8 = 0; r8 < 8; ++r8) {
        int r = rg * 8 + r8;
        float a = 0.0f;
#pragma unroll
        for (int k = 0; k < 64; k += 4) {
            float4 xv = *((const float4*)&xs[r][k]);   // broadcast across wave
            a += xv.x * w[k] + xv.y * w[k + 1] + xv.z * w[k + 2] + xv.w * w[k + 3];
        }
        acc[r8] = a;
    }
#pragma unroll
    for (int r8 = 0; r8 < 8; ++r8)
        XW[(size_t)(row0 + rg * 8 + r8) * 64 + col] = acc[r8];
}

// ---------------- aggregation: CSR gather, 4 groups x 4-deep unroll ----------------
// Wave = 1 node. 4 groups of 16 lanes; lane holds float4 (sub = lane&15).
// Group g walks edges e0+g with stride 4, unrolled x4 with 4 accumulators
// -> up to 16 independent 256B row-gathers in flight per wave.
// out = di * (di*row_self + sum dinv[s]*row_s)
__global__ __launch_bounds__(256) void k_agg(const float* __restrict__ XW,
                                             const int* __restrict__ off,
                                             const int* __restrict__ esrc,
                                             const float* __restrict__ dinv,
                                             float* __restrict__ out) {
    const float4* __restrict__ XW4 = (const float4*)XW;
    int node = blockIdx.x * 4 + (threadIdx.x >> 6);
    int lane = threadIdx.x & 63;
    int grp  = lane >> 4;                  // 0..3
    int sub  = lane & 15;                  // float4 slot within row

    float di = dinv[node];
    float sl = (grp == 0) ? di : 0.0f;
    float4 row = XW4[(size_t)node * 16 + sub];
    float4 a0 = make_float4(sl * row.x, sl * row.y, sl * row.z, sl * row.w);
    float4 a1 = make_float4(0.f, 0.f, 0.f, 0.f);
    float4 a2 = make_float4(0.f, 0.f, 0.f, 0.f);
    float4 a3 = make_float4(0.f, 0.f, 0.f, 0.f);

    int e0 = off[node], e1 = off[node + 1];
    int e = e0 + grp;
    for (; e + 12 < e1; e += 16) {
        int s0 = esrc[e];
        int s1 = esrc[e + 4];
        int s2 = esrc[e + 8];
        int s3 = esrc[e + 12];
        float n0 = dinv[s0], n1 = dinv[s1], n2 = dinv[s2], n3 = dinv[s3];
        float4 r0 = XW4[(size_t)s0 * 16 + sub];
        float4 r1 = XW4[(size_t)s1 * 16 + sub];
        float4 r2 = XW4[(size_t)s2 * 16 + sub];
        float4 r3 = XW4[(size_t)s3 * 16 + sub];
        a0.x += n0 * r0.x; a0.y += n0 * r0.y; a0.z += n0 * r0.z; a0.w += n0 * r0.w;
        a1.x += n1 * r1.x; a1.y += n1 * r1.y; a1.z += n1 * r1.z; a1.w += n1 * r1.w;
        a2.x += n2 * r2.x; a2.y += n2 * r2.y; a2.z += n2 * r2.z; a2.w += n2 * r2.w;
        a3.x += n3 * r3.x; a3.y += n3 * r3.y; a3.z += n3 * r3.z; a3.w += n3 * r3.w;
    }
    for (; e < e1; e += 4) {
        int s = esrc[e];
        float n = dinv[s];
        float4 r = XW4[(size_t)s * 16 + sub];
        a0.x += n * r.x; a0.y += n * r.y; a0.z += n * r.z; a0.w += n * r.w;
    }
    a0.x += a1.x + a2.x + a3.x;
    a0.y += a1.y + a2.y + a3.y;
    a0.z += a1.z + a2.z + a3.z;
    a0.w += a1.w + a2.w + a3.w;

    // reduce across the 4 groups (lane bits 4,5)
#pragma unroll
    for (int m = 16; m <= 32; m <<= 1) {
        a0.x += __shfl_xor(a0.x, m);
        a0.y += __shfl_xor(a0.y, m);
        a0.z += __shfl_xor(a0.z, m);
        a0.w += __shfl_xor(a0.w, m);
    }
    if (grp == 0) {
        a0.x *= di; a0.y *= di; a0.z *= di; a0.w *= di;
        ((float4*)out)[(size_t)node * 16 + sub] = a0;
    }
}

// ---------------- BN stats: column sums and sumsq ----------------
__global__ __launch_bounds__(256) void k_stats(const float* __restrict__ X,
                                               float* __restrict__ stats, int n) {
    __shared__ float ls[4][64], lq[4][64];
    int lane = threadIdx.x & 63, rg = threadIdx.x >> 6;
    float s = 0.0f, sq = 0.0f;
    for (int r = blockIdx.x * 4 + rg; r < n; r += gridDim.x * 4) {
        float v = X[(size_t)r * 64 + lane];
        s += v; sq += v * v;
    }
    ls[rg][lane] = s; lq[rg][lane] = sq;
    __syncthreads();
    if (rg == 0) {
        s  = ls[0][lane] + ls[1][lane] + ls[2][lane] + ls[3][lane];
        sq = lq[0][lane] + lq[1][lane] + lq[2][lane] + lq[3][lane];
        atomicAdd(&stats[lane], s);
        atomicAdd(&stats[64 + lane], sq);
    }
}

// ---------------- BN apply + leaky_relu (out-of-place) ----------------
__global__ __launch_bounds__(256) void k_bnact(const float* __restrict__ X,
                                               float* __restrict__ Y,
                                               const float* __restrict__ stats,
                                               const float* __restrict__ gamma,
                                               const float* __restrict__ beta,
                                               int n) {
    int lane = threadIdx.x & 63, rg = threadIdx.x >> 6;
    float inv_n = 1.0f / (float)n;
    float mu  = stats[lane] * inv_n;
    float var = stats[64 + lane] * inv_n - mu * mu;
    float sc  = gamma[lane] * rsqrtf(var + EPS);
    float sh  = beta[lane] - sc * mu;
    for (int r = blockIdx.x * 4 + rg; r < n; r += gridDim.x * 4) {
        float v = X[(size_t)r * 64 + lane];
        v = sc * v + sh;
        Y[(size_t)r * 64 + lane] = fmaxf(v, 0.01f * v);
    }
}

extern "C" void kernel_launch(void* const* d_in, const int* in_sizes, int n_in,
                              void* d_out, int out_size, void* d_ws, size_t ws_size,
                              hipStream_t stream) {
    const float* x   = (const float*)d_in[0];
    const int*   ei  = (const int*)d_in[1];
    const int*   src = ei;
    const int*   dst = ei + NE;
    const float* W1  = (const float*)d_in[2];
    const float* g1  = (const float*)d_in[4];
    const float* be1 = (const float*)d_in[5];
    const float* W2  = (const float*)d_in[6];
    const float* g2  = (const float*)d_in[8];
    const float* be2 = (const float*)d_in[9];
    float* out = (float*)d_out;

    char* ws = (char*)d_ws;
    size_t p = 0;
    auto alloc = [&](size_t bytes) {
        size_t o = p;
        p = (p + bytes + 255) & ~(size_t)255;
        return o;
    };
    int*   cntdinv = (int*)(ws + alloc((size_t)NN * 4));        // counts, then dinv
    int*   off     = (int*)(ws + alloc((size_t)(NN + 1) * 4));
    int*   cur     = (int*)(ws + alloc((size_t)NN * 4));
    int*   bsum    = (int*)(ws + alloc(1024));
    int*   esrc    = (int*)(ws + alloc((size_t)NE * 4));
    float* stats   = (float*)(ws + alloc(1024));                // 128 per layer
    float* A       = (float*)(ws + alloc((size_t)NN * DD * 4)); // xw / h2 staging
    float* B       = (float*)(ws + alloc((size_t)NN * DD * 4)); // raw agg
    (void)ws_size; (void)in_sizes; (void)n_in; (void)out_size;

    float* dinv = (float*)cntdinv;

    hipMemsetAsync(cntdinv, 0, (size_t)NN * 4, stream);
    hipMemsetAsync(stats, 0, 1024, stream);

    int nq = NE / 4;  // 300000, NE % 4 == 0
    k_deg<<<(nq + 255) / 256, 256, 0, stream>>>(dst, cntdinv, nq);

    int nb = (NN + 511) / 512;  // 196
    k_scan1<<<nb, 512, 0, stream>>>(cntdinv, off, bsum, NN);
    k_scan2<<<1, 256, 0, stream>>>(bsum, nb);
    k_scan3<<<nb, 512, 0, stream>>>(off, bsum, NN, NE);

    k_dinv<<<(NN + 255) / 256, 256, 0, stream>>>(cntdinv, NN);

    hipMemcpyAsync(cur, off, (size_t)NN * 4, hipMemcpyDeviceToDevice, stream);
    k_fill<<<(nq + 255) / 256, 256, 0, stream>>>(src, dst, cur, esrc, nq);

    // ---- layer 1 ----
    k_gemm<false><<<NN / 32, 256, 0, stream>>>(x, W1, A, nullptr, nullptr, nullptr);
    k_agg<<<NN / 4, 256, 0, stream>>>(A, off, esrc, dinv, B);      // B = raw agg1
    k_stats<<<512, 256, 0, stream>>>(B, stats, NN);

    // ---- layer 2 (BN1+leaky fused into gemm's x-load) ----
    k_gemm<true><<<NN / 32, 256, 0, stream>>>(B, W2, A, stats, g1, be1);
    k_agg<<<NN / 4, 256, 0, stream>>>(A, off, esrc, dinv, B);      // B = raw agg2
    k_stats<<<512, 256, 0, stream>>>(B, stats + 128, NN);
    k_bnact<<<1024, 256, 0, stream>>>(B, out, stats + 128, g2, be2, NN);
}

// Round 6
// 441.605 us; speedup vs baseline: 1.0188x; 1.0188x over previous
//
#include <hip/hip_runtime.h>

#define NN 100000
#define NE 1200000
#define DD 64
#define EPS 1e-5f

#define GEMM_BLOCKS (NN / 32)          // 3125
#define DEG_BLOCKS  ((NE + 255) / 256) // 4688

// ---------------- GEMM tile body (shared by layer1-fused and layer2) ----------------
template <bool BN>
__device__ __forceinline__ void gemm_tile(const float* __restrict__ X,
                                          const float* __restrict__ W,
                                          float* __restrict__ XW,
                                          const float* __restrict__ stats,
                                          const float* __restrict__ gamma,
                                          const float* __restrict__ beta,
                                          int blk) {
    __shared__ float xs[32][64];
    __shared__ float sc_s[64], sh_s[64];
    int col = threadIdx.x & 63;
    int rg  = threadIdx.x >> 6;            // 0..3
    int row0 = blk * 32;

    if (BN) {
        if (threadIdx.x < 64) {
            const float inv_n = 1.0f / (float)NN;
            float mu  = stats[threadIdx.x] * inv_n;
            float var = stats[64 + threadIdx.x] * inv_n - mu * mu;
            float sc  = gamma[threadIdx.x] * rsqrtf(var + EPS);
            sc_s[threadIdx.x] = sc;
            sh_s[threadIdx.x] = beta[threadIdx.x] - sc * mu;
        }
        __syncthreads();
    }

    // W column in registers (reads coalesced across lanes, L2-hot across blocks)
    float w[64];
#pragma unroll
    for (int k = 0; k < 64; ++k) w[k] = W[k * 64 + col];

    // stage 32x64 x-tile (fully coalesced float4 loads), optional BN+leaky
    for (int i = threadIdx.x; i < 32 * 16; i += 256) {
        int r = i >> 4, c4 = i & 15;
        float4 v = ((const float4*)(X + (size_t)(row0 + r) * 64))[c4];
        if (BN) {
            float4 s4 = ((const float4*)sc_s)[c4];
            float4 h4 = ((const float4*)sh_s)[c4];
            v.x = s4.x * v.x + h4.x; v.x = fmaxf(v.x, 0.01f * v.x);
            v.y = s4.y * v.y + h4.y; v.y = fmaxf(v.y, 0.01f * v.y);
            v.z = s4.z * v.z + h4.z; v.z = fmaxf(v.z, 0.01f * v.z);
            v.w = s4.w * v.w + h4.w; v.w = fmaxf(v.w, 0.01f * v.w);
        }
        ((float4*)&xs[r][0])[c4] = v;
    }
    __syncthreads();

    float acc[8];
#pragma unroll
    for (int r8 = 0; r8 < 8; ++r8) {
        int r = rg * 8 + r8;
        float a = 0.0f;
#pragma unroll
        for (int k = 0; k < 64; k += 4) {
            float4 xv = *((const float4*)&xs[r][k]);   // broadcast across wave
            a += xv.x * w[k] + xv.y * w[k + 1] + xv.z * w[k + 2] + xv.w * w[k + 3];
        }
        acc[r8] = a;
    }
#pragma unroll
    for (int r8 = 0; r8 < 8; ++r8)
        XW[(size_t)(row0 + rg * 8 + r8) * 64 + col] = acc[r8];
}

// ---------------- fused: degree histogram (first) + GEMM1 (after) ----------------
// deg blocks dispatched first so their latency-bound atomics overlap gemm compute.
__global__ __launch_bounds__(256) void k_l1(const float* __restrict__ X,
                                            const float* __restrict__ W,
                                            float* __restrict__ XW,
                                            const int* __restrict__ dst,
                                            int* __restrict__ cnt) {
    if (blockIdx.x < DEG_BLOCKS) {
        int i = blockIdx.x * 256 + threadIdx.x;
        if (i < NE) atomicAdd(&cnt[dst[i]], 1);
    } else {
        gemm_tile<false>(X, W, XW, nullptr, nullptr, nullptr, blockIdx.x - DEG_BLOCKS);
    }
}

// ---------------- layer-2 GEMM with fused BN1+leaky on input ----------------
__global__ __launch_bounds__(256) void k_gemm2(const float* __restrict__ X,
                                               const float* __restrict__ W,
                                               float* __restrict__ XW,
                                               const float* __restrict__ stats,
                                               const float* __restrict__ gamma,
                                               const float* __restrict__ beta) {
    gemm_tile<true>(X, W, XW, stats, gamma, beta, blockIdx.x);
}

// ---------------- hierarchical exclusive scan of counts -> offsets ----------------
__global__ __launch_bounds__(512) void k_scan1(const int* __restrict__ cnt,
                                               int* __restrict__ out,
                                               int* __restrict__ bsum, int n) {
    __shared__ int s[512];
    int t = threadIdx.x;
    int i = blockIdx.x * 512 + t;
    int v = (i < n) ? cnt[i] : 0;
    s[t] = v;
    __syncthreads();
    for (int off = 1; off < 512; off <<= 1) {
        int u = (t >= off) ? s[t - off] : 0;
        __syncthreads();
        s[t] += u;
        __syncthreads();
    }
    if (i < n) out[i] = s[t] - v;          // block-local exclusive
    if (t == 511) bsum[blockIdx.x] = s[511];
}

__global__ __launch_bounds__(256) void k_scan2(int* __restrict__ bsum, int nb) {
    __shared__ int s[256];
    int t = threadIdx.x;
    int v = (t < nb) ? bsum[t] : 0;
    s[t] = v;
    __syncthreads();
    for (int off = 1; off < 256; off <<= 1) {
        int u = (t >= off) ? s[t - off] : 0;
        __syncthreads();
        s[t] += u;
        __syncthreads();
    }
    if (t < nb) bsum[t] = s[t] - v;        // exclusive scan of block sums
}

// scan3 fused with: cursor init (cur = off) and dinv = rsqrt(cnt+1) in-place.
// Safe: scan1 (the only reader of raw cnt) fully completed at a kernel boundary.
__global__ __launch_bounds__(512) void k_scan3(int* __restrict__ out,
                                               const int* __restrict__ bsum,
                                               int* __restrict__ cnt_dinv,
                                               int* __restrict__ cur,
                                               int n, int e) {
    int i = blockIdx.x * 512 + threadIdx.x;
    if (i < n) {
        int v = out[i] + bsum[blockIdx.x];
        out[i] = v;
        cur[i] = v;
        float dv = rsqrtf((float)cnt_dinv[i] + 1.0f);
        ((float*)cnt_dinv)[i] = dv;
    }
    if (i == 0) out[n] = e;                // total = E always
}

// ---------------- CSR fill (src-only 4B records), 1 edge/thread, NT store ----------------
__global__ __launch_bounds__(256) void k_fill(const int* __restrict__ src,
                                              const int* __restrict__ dst,
                                              int* __restrict__ cursor,
                                              int* __restrict__ esrc, int e) {
    int i = blockIdx.x * 256 + threadIdx.x;
    if (i < e) {
        int pos = atomicAdd(&cursor[dst[i]], 1);
        __builtin_nontemporal_store(src[i], &esrc[pos]);
    }
}

// ---------------- aggregation: CSR gather, 4 groups x 4-deep unroll ----------------
// Wave = 1 node. 4 groups of 16 lanes; lane holds float4 (sub = lane&15).
// Group g walks edges e0+g with stride 4, unrolled x4 with 4 accumulators
// -> up to 16 independent 256B row-gathers in flight per wave.
// out = di * (di*row_self + sum dinv[s]*row_s)
__global__ __launch_bounds__(256) void k_agg(const float* __restrict__ XW,
                                             const int* __restrict__ off,
                                             const int* __restrict__ esrc,
                                             const float* __restrict__ dinv,
                                             float* __restrict__ out) {
    const float4* __restrict__ XW4 = (const float4*)XW;
    int node = blockIdx.x * 4 + (threadIdx.x >> 6);
    int lane = threadIdx.x & 63;
    int grp  = lane >> 4;                  // 0..3
    int sub  = lane & 15;                  // float4 slot within row

    float di = dinv[node];
    float sl = (grp == 0) ? di : 0.0f;
    float4 row = XW4[(size_t)node * 16 + sub];
    float4 a0 = make_float4(sl * row.x, sl * row.y, sl * row.z, sl * row.w);
    float4 a1 = make_float4(0.f, 0.f, 0.f, 0.f);
    float4 a2 = make_float4(0.f, 0.f, 0.f, 0.f);
    float4 a3 = make_float4(0.f, 0.f, 0.f, 0.f);

    int e0 = off[node], e1 = off[node + 1];
    int e = e0 + grp;
    for (; e + 12 < e1; e += 16) {
        int s0 = esrc[e];
        int s1 = esrc[e + 4];
        int s2 = esrc[e + 8];
        int s3 = esrc[e + 12];
        float n0 = dinv[s0], n1 = dinv[s1], n2 = dinv[s2], n3 = dinv[s3];
        float4 r0 = XW4[(size_t)s0 * 16 + sub];
        float4 r1 = XW4[(size_t)s1 * 16 + sub];
        float4 r2 = XW4[(size_t)s2 * 16 + sub];
        float4 r3 = XW4[(size_t)s3 * 16 + sub];
        a0.x += n0 * r0.x; a0.y += n0 * r0.y; a0.z += n0 * r0.z; a0.w += n0 * r0.w;
        a1.x += n1 * r1.x; a1.y += n1 * r1.y; a1.z += n1 * r1.z; a1.w += n1 * r1.w;
        a2.x += n2 * r2.x; a2.y += n2 * r2.y; a2.z += n2 * r2.z; a2.w += n2 * r2.w;
        a3.x += n3 * r3.x; a3.y += n3 * r3.y; a3.z += n3 * r3.z; a3.w += n3 * r3.w;
    }
    for (; e < e1; e += 4) {
        int s = esrc[e];
        float n = dinv[s];
        float4 r = XW4[(size_t)s * 16 + sub];
        a0.x += n * r.x; a0.y += n * r.y; a0.z += n * r.z; a0.w += n * r.w;
    }
    a0.x += a1.x + a2.x + a3.x;
    a0.y += a1.y + a2.y + a3.y;
    a0.z += a1.z + a2.z + a3.z;
    a0.w += a1.w + a2.w + a3.w;

    // reduce across the 4 groups (lane bits 4,5)
#pragma unroll
    for (int m = 16; m <= 32; m <<= 1) {
        a0.x += __shfl_xor(a0.x, m);
        a0.y += __shfl_xor(a0.y, m);
        a0.z += __shfl_xor(a0.z, m);
        a0.w += __shfl_xor(a0.w, m);
    }
    if (grp == 0) {
        a0.x *= di; a0.y *= di; a0.z *= di; a0.w *= di;
        ((float4*)out)[(size_t)node * 16 + sub] = a0;
    }
}

// ---------------- BN stats: column sums and sumsq ----------------
__global__ __launch_bounds__(256) void k_stats(const float* __restrict__ X,
                                               float* __restrict__ stats, int n) {
    __shared__ float ls[4][64], lq[4][64];
    int lane = threadIdx.x & 63, rg = threadIdx.x >> 6;
    float s = 0.0f, sq = 0.0f;
    for (int r = blockIdx.x * 4 + rg; r < n; r += gridDim.x * 4) {
        float v = X[(size_t)r * 64 + lane];
        s += v; sq += v * v;
    }
    ls[rg][lane] = s; lq[rg][lane] = sq;
    __syncthreads();
    if (rg == 0) {
        s  = ls[0][lane] + ls[1][lane] + ls[2][lane] + ls[3][lane];
        sq = lq[0][lane] + lq[1][lane] + lq[2][lane] + lq[3][lane];
        atomicAdd(&stats[lane], s);
        atomicAdd(&stats[64 + lane], sq);
    }
}

// ---------------- BN apply + leaky_relu (out-of-place) ----------------
__global__ __launch_bounds__(256) void k_bnact(const float* __restrict__ X,
                                               float* __restrict__ Y,
                                               const float* __restrict__ stats,
                                               const float* __restrict__ gamma,
                                               const float* __restrict__ beta,
                                               int n) {
    int lane = threadIdx.x & 63, rg = threadIdx.x >> 6;
    float inv_n = 1.0f / (float)n;
    float mu  = stats[lane] * inv_n;
    float var = stats[64 + lane] * inv_n - mu * mu;
    float sc  = gamma[lane] * rsqrtf(var + EPS);
    float sh  = beta[lane] - sc * mu;
    for (int r = blockIdx.x * 4 + rg; r < n; r += gridDim.x * 4) {
        float v = X[(size_t)r * 64 + lane];
        v = sc * v + sh;
        Y[(size_t)r * 64 + lane] = fmaxf(v, 0.01f * v);
    }
}

extern "C" void kernel_launch(void* const* d_in, const int* in_sizes, int n_in,
                              void* d_out, int out_size, void* d_ws, size_t ws_size,
                              hipStream_t stream) {
    const float* x   = (const float*)d_in[0];
    const int*   ei  = (const int*)d_in[1];
    const int*   src = ei;
    const int*   dst = ei + NE;
    const float* W1  = (const float*)d_in[2];
    const float* g1  = (const float*)d_in[4];
    const float* be1 = (const float*)d_in[5];
    const float* W2  = (const float*)d_in[6];
    const float* g2  = (const float*)d_in[8];
    const float* be2 = (const float*)d_in[9];
    float* out = (float*)d_out;

    char* ws = (char*)d_ws;
    size_t p = 0;
    auto alloc = [&](size_t bytes) {
        size_t o = p;
        p = (p + bytes + 255) & ~(size_t)255;
        return o;
    };
    int*   cntdinv = (int*)(ws + alloc((size_t)NN * 4));        // counts, then dinv
    int*   off     = (int*)(ws + alloc((size_t)(NN + 1) * 4));
    int*   cur     = (int*)(ws + alloc((size_t)NN * 4));
    int*   bsum    = (int*)(ws + alloc(1024));
    int*   esrc    = (int*)(ws + alloc((size_t)NE * 4));
    float* stats   = (float*)(ws + alloc(1024));                // 128 per layer
    float* A       = (float*)(ws + alloc((size_t)NN * DD * 4)); // xw / h2 staging
    float* B       = (float*)(ws + alloc((size_t)NN * DD * 4)); // raw agg
    (void)ws_size; (void)in_sizes; (void)n_in; (void)out_size;

    float* dinv = (float*)cntdinv;

    hipMemsetAsync(cntdinv, 0, (size_t)NN * 4, stream);
    hipMemsetAsync(stats, 0, 1024, stream);

    // ---- CSR build overlapped with layer-1 GEMM ----
    k_l1<<<DEG_BLOCKS + GEMM_BLOCKS, 256, 0, stream>>>(x, W1, A, dst, cntdinv);

    int nb = (NN + 511) / 512;  // 196
    k_scan1<<<nb, 512, 0, stream>>>(cntdinv, off, bsum, NN);
    k_scan2<<<1, 256, 0, stream>>>(bsum, nb);
    k_scan3<<<nb, 512, 0, stream>>>(off, bsum, cntdinv, cur, NN, NE);  // + dinv + cur

    k_fill<<<DEG_BLOCKS, 256, 0, stream>>>(src, dst, cur, esrc, NE);

    // ---- layer 1 aggregation + stats ----
    k_agg<<<NN / 4, 256, 0, stream>>>(A, off, esrc, dinv, B);      // B = raw agg1
    k_stats<<<512, 256, 0, stream>>>(B, stats, NN);

    // ---- layer 2 (BN1+leaky fused into gemm's x-load) ----
    k_gemm2<<<GEMM_BLOCKS, 256, 0, stream>>>(B, W2, A, stats, g1, be1);
    k_agg<<<NN / 4, 256, 0, stream>>>(A, off, esrc, dinv, B);      // B = raw agg2
    k_stats<<<512, 256, 0, stream>>>(B, stats + 128, NN);
    k_bnact<<<1024, 256, 0, stream>>>(B, out, stats + 128, g2, be2, NN);
}

// Round 7
// 335.665 us; speedup vs baseline: 1.3404x; 1.3156x over previous
//
#include <hip/hip_runtime.h>

#define NN 100000
#define NE 1200000
#define DD 64
#define EPS 1e-5f

#define NB 196                             // ceil(NN/512) dst buckets
#define GEMM_BLOCKS (NN / 32)              // 3125
#define HIST_BLOCKS 256
#define PART_BLOCKS 256
#define EPH ((NE + HIST_BLOCKS - 1) / HIST_BLOCKS)   // 4688 edges per hist slice
#define EPB ((NE + PART_BLOCKS - 1) / PART_BLOCKS)   // 4688 edges per part slice

// ---------------- GEMM tile body (shared by layer1-fused and layer2) ----------------
template <bool BN>
__device__ __forceinline__ void gemm_tile(const float* __restrict__ X,
                                          const float* __restrict__ W,
                                          float* __restrict__ XW,
                                          const float* __restrict__ stats,
                                          const float* __restrict__ gamma,
                                          const float* __restrict__ beta,
                                          int blk) {
    __shared__ float xs[32][64];
    __shared__ float sc_s[64], sh_s[64];
    int col = threadIdx.x & 63;
    int rg  = threadIdx.x >> 6;            // 0..3
    int row0 = blk * 32;

    if (BN) {
        if (threadIdx.x < 64) {
            const float inv_n = 1.0f / (float)NN;
            float mu  = stats[threadIdx.x] * inv_n;
            float var = stats[64 + threadIdx.x] * inv_n - mu * mu;
            float sc  = gamma[threadIdx.x] * rsqrtf(var + EPS);
            sc_s[threadIdx.x] = sc;
            sh_s[threadIdx.x] = beta[threadIdx.x] - sc * mu;
        }
        __syncthreads();
    }

    float w[64];
#pragma unroll
    for (int k = 0; k < 64; ++k) w[k] = W[k * 64 + col];

    for (int i = threadIdx.x; i < 32 * 16; i += 256) {
        int r = i >> 4, c4 = i & 15;
        float4 v = ((const float4*)(X + (size_t)(row0 + r) * 64))[c4];
        if (BN) {
            float4 s4 = ((const float4*)sc_s)[c4];
            float4 h4 = ((const float4*)sh_s)[c4];
            v.x = s4.x * v.x + h4.x; v.x = fmaxf(v.x, 0.01f * v.x);
            v.y = s4.y * v.y + h4.y; v.y = fmaxf(v.y, 0.01f * v.y);
            v.z = s4.z * v.z + h4.z; v.z = fmaxf(v.z, 0.01f * v.z);
            v.w = s4.w * v.w + h4.w; v.w = fmaxf(v.w, 0.01f * v.w);
        }
        ((float4*)&xs[r][0])[c4] = v;
    }
    __syncthreads();

    float acc[8];
#pragma unroll
    for (int r8 = 0; r8 < 8; ++r8) {
        int r = rg * 8 + r8;
        float a = 0.0f;
#pragma unroll
        for (int k = 0; k < 64; k += 4) {
            float4 xv = *((const float4*)&xs[r][k]);
            a += xv.x * w[k] + xv.y * w[k + 1] + xv.z * w[k + 2] + xv.w * w[k + 3];
        }
        acc[r8] = a;
    }
#pragma unroll
    for (int r8 = 0; r8 < 8; ++r8)
        XW[(size_t)(row0 + rg * 8 + r8) * 64 + col] = acc[r8];
}

// ---------------- fused: coarse bucket histogram (first) + GEMM1 (after) ----------------
__global__ __launch_bounds__(256) void k_l1(const float* __restrict__ X,
                                            const float* __restrict__ W,
                                            float* __restrict__ XW,
                                            const int* __restrict__ dst,
                                            int* __restrict__ cnt196) {
    if (blockIdx.x < HIST_BLOCKS) {
        __shared__ int h[NB];
        for (int t = threadIdx.x; t < NB; t += 256) h[t] = 0;
        __syncthreads();
        int s0 = blockIdx.x * EPH;
        int s1 = s0 + EPH; if (s1 > NE) s1 = NE;
        for (int i = s0 + threadIdx.x; i < s1; i += 256)
            atomicAdd(&h[dst[i] >> 9], 1);
        __syncthreads();
        for (int t = threadIdx.x; t < NB; t += 256)
            if (h[t]) atomicAdd(&cnt196[t], h[t]);
    } else {
        gemm_tile<false>(X, W, XW, nullptr, nullptr, nullptr,
                         (int)blockIdx.x - HIST_BLOCKS);
    }
}

// ---------------- layer-2 GEMM with fused BN1+leaky on input ----------------
__global__ __launch_bounds__(256) void k_gemm2(const float* __restrict__ X,
                                               const float* __restrict__ W,
                                               float* __restrict__ XW,
                                               const float* __restrict__ stats,
                                               const float* __restrict__ gamma,
                                               const float* __restrict__ beta) {
    gemm_tile<true>(X, W, XW, stats, gamma, beta, blockIdx.x);
}

// ---------------- tiny scan of 196 bucket counts -> bucket offsets + cursors ----------------
__global__ __launch_bounds__(256) void k_scanb(const int* __restrict__ cnt196,
                                               int* __restrict__ bo,
                                               int* __restrict__ cur) {
    __shared__ int s[256];
    int t = threadIdx.x;
    int v = (t < NB) ? cnt196[t] : 0;
    s[t] = v;
    __syncthreads();
    for (int o = 1; o < 256; o <<= 1) {
        int u = (t >= o) ? s[t - o] : 0;
        __syncthreads();
        s[t] += u;
        __syncthreads();
    }
    if (t < NB) {
        int ex = s[t] - v;
        bo[t] = ex;
        cur[t] = ex;
    }
    if (t == 0) bo[NB] = NE;
}

// ---------------- partition edges into 196 dst-buckets (packed 4B records) ----------------
// record = src | (local_dst << 17); src < 2^17, local_dst < 512.
// Per-WG: LDS hist -> one atomic reserve per bucket -> placement via LDS cursors.
// Each (WG,bucket) writes a contiguous ~24-record run -> minimal write amplification.
__global__ __launch_bounds__(256) void k_part(const int* __restrict__ src,
                                              const int* __restrict__ dst,
                                              int* __restrict__ cur,
                                              int* __restrict__ ebuf) {
    __shared__ int h[NB];
    for (int t = threadIdx.x; t < NB; t += 256) h[t] = 0;
    __syncthreads();
    int s0 = blockIdx.x * EPB;
    int s1 = s0 + EPB; if (s1 > NE) s1 = NE;
    for (int i = s0 + threadIdx.x; i < s1; i += 256)
        atomicAdd(&h[dst[i] >> 9], 1);
    __syncthreads();
    for (int t = threadIdx.x; t < NB; t += 256) {
        int c = h[t];
        h[t] = c ? atomicAdd(&cur[t], c) : 0;
    }
    __syncthreads();
    for (int i = s0 + threadIdx.x; i < s1; i += 256) {
        int d = dst[i];
        int p = atomicAdd(&h[d >> 9], 1);
        ebuf[p] = src[i] | ((d & 511) << 17);
    }
}

// ---------------- per-bucket: degrees -> dinv, local scan -> off, local fill -> esrc ----
// One WG (512 thr) owns one bucket: all LDS atomics local, esrc writes land in the
// bucket's own contiguous region (single-CU lines, written back once).
__global__ __launch_bounds__(512) void k_bucket(const int* __restrict__ ebuf,
                                                const int* __restrict__ bo,
                                                int* __restrict__ off,
                                                float* __restrict__ dinv,
                                                int* __restrict__ esrc) {
    __shared__ int s[512];
    int b = blockIdx.x, t = threadIdx.x;
    int base = b << 9;
    int e0 = bo[b], e1 = bo[b + 1];
    s[t] = 0;
    __syncthreads();
    for (int e = e0 + t; e < e1; e += 512)
        atomicAdd(&s[ebuf[e] >> 17], 1);
    __syncthreads();
    int deg = s[t];
    if (base + t < NN) dinv[base + t] = rsqrtf((float)deg + 1.0f);
    // inclusive scan of degrees
    for (int o = 1; o < 512; o <<= 1) {
        int u = (t >= o) ? s[t - o] : 0;
        __syncthreads();
        s[t] += u;
        __syncthreads();
    }
    int gstart = e0 + s[t] - deg;          // global CSR start of node base+t
    if (base + t < NN) off[base + t] = gstart;
    if (b == NB - 1 && t == 0) off[NN] = NE;
    __syncthreads();
    s[t] = gstart;                          // LDS write-cursor per local node
    __syncthreads();
    for (int e = e0 + t; e < e1; e += 512) {
        int v = ebuf[e];
        int p = atomicAdd(&s[v >> 17], 1);
        esrc[p] = v & 0x1FFFF;
    }
}

// ---------------- aggregation: CSR gather, 4 groups x 4-deep unroll ----------------
__global__ __launch_bounds__(256) void k_agg(const float* __restrict__ XW,
                                             const int* __restrict__ off,
                                             const int* __restrict__ esrc,
                                             const float* __restrict__ dinv,
                                             float* __restrict__ out) {
    const float4* __restrict__ XW4 = (const float4*)XW;
    int node = blockIdx.x * 4 + (threadIdx.x >> 6);
    int lane = threadIdx.x & 63;
    int grp  = lane >> 4;
    int sub  = lane & 15;

    float di = dinv[node];
    float sl = (grp == 0) ? di : 0.0f;
    float4 row = XW4[(size_t)node * 16 + sub];
    float4 a0 = make_float4(sl * row.x, sl * row.y, sl * row.z, sl * row.w);
    float4 a1 = make_float4(0.f, 0.f, 0.f, 0.f);
    float4 a2 = make_float4(0.f, 0.f, 0.f, 0.f);
    float4 a3 = make_float4(0.f, 0.f, 0.f, 0.f);

    int e0 = off[node], e1 = off[node + 1];
    int e = e0 + grp;
    for (; e + 12 < e1; e += 16) {
        int s0 = esrc[e];
        int s1 = esrc[e + 4];
        int s2 = esrc[e + 8];
        int s3 = esrc[e + 12];
        float n0 = dinv[s0], n1 = dinv[s1], n2 = dinv[s2], n3 = dinv[s3];
        float4 r0 = XW4[(size_t)s0 * 16 + sub];
        float4 r1 = XW4[(size_t)s1 * 16 + sub];
        float4 r2 = XW4[(size_t)s2 * 16 + sub];
        float4 r3 = XW4[(size_t)s3 * 16 + sub];
        a0.x += n0 * r0.x; a0.y += n0 * r0.y; a0.z += n0 * r0.z; a0.w += n0 * r0.w;
        a1.x += n1 * r1.x; a1.y += n1 * r1.y; a1.z += n1 * r1.z; a1.w += n1 * r1.w;
        a2.x += n2 * r2.x; a2.y += n2 * r2.y; a2.z += n2 * r2.z; a2.w += n2 * r2.w;
        a3.x += n3 * r3.x; a3.y += n3 * r3.y; a3.z += n3 * r3.z; a3.w += n3 * r3.w;
    }
    for (; e < e1; e += 4) {
        int s = esrc[e];
        float n = dinv[s];
        float4 r = XW4[(size_t)s * 16 + sub];
        a0.x += n * r.x; a0.y += n * r.y; a0.z += n * r.z; a0.w += n * r.w;
    }
    a0.x += a1.x + a2.x + a3.x;
    a0.y += a1.y + a2.y + a3.y;
    a0.z += a1.z + a2.z + a3.z;
    a0.w += a1.w + a2.w + a3.w;

#pragma unroll
    for (int m = 16; m <= 32; m <<= 1) {
        a0.x += __shfl_xor(a0.x, m);
        a0.y += __shfl_xor(a0.y, m);
        a0.z += __shfl_xor(a0.z, m);
        a0.w += __shfl_xor(a0.w, m);
    }
    if (grp == 0) {
        a0.x *= di; a0.y *= di; a0.z *= di; a0.w *= di;
        ((float4*)out)[(size_t)node * 16 + sub] = a0;
    }
}

// ---------------- BN stats: column sums and sumsq ----------------
__global__ __launch_bounds__(256) void k_stats(const float* __restrict__ X,
                                               float* __restrict__ stats, int n) {
    __shared__ float ls[4][64], lq[4][64];
    int lane = threadIdx.x & 63, rg = threadIdx.x >> 6;
    float s = 0.0f, sq = 0.0f;
    for (int r = blockIdx.x * 4 + rg; r < n; r += gridDim.x * 4) {
        float v = X[(size_t)r * 64 + lane];
        s += v; sq += v * v;
    }
    ls[rg][lane] = s; lq[rg][lane] = sq;
    __syncthreads();
    if (rg == 0) {
        s  = ls[0][lane] + ls[1][lane] + ls[2][lane] + ls[3][lane];
        sq = lq[0][lane] + lq[1][lane] + lq[2][lane] + lq[3][lane];
        atomicAdd(&stats[lane], s);
        atomicAdd(&stats[64 + lane], sq);
    }
}

// ---------------- BN apply + leaky_relu (out-of-place) ----------------
__global__ __launch_bounds__(256) void k_bnact(const float* __restrict__ X,
                                               float* __restrict__ Y,
                                               const float* __restrict__ stats,
                                               const float* __restrict__ gamma,
                                               const float* __restrict__ beta,
                                               int n) {
    int lane = threadIdx.x & 63, rg = threadIdx.x >> 6;
    float inv_n = 1.0f / (float)n;
    float mu  = stats[lane] * inv_n;
    float var = stats[64 + lane] * inv_n - mu * mu;
    float sc  = gamma[lane] * rsqrtf(var + EPS);
    float sh  = beta[lane] - sc * mu;
    for (int r = blockIdx.x * 4 + rg; r < n; r += gridDim.x * 4) {
        float v = X[(size_t)r * 64 + lane];
        v = sc * v + sh;
        Y[(size_t)r * 64 + lane] = fmaxf(v, 0.01f * v);
    }
}

extern "C" void kernel_launch(void* const* d_in, const int* in_sizes, int n_in,
                              void* d_out, int out_size, void* d_ws, size_t ws_size,
                              hipStream_t stream) {
    const float* x   = (const float*)d_in[0];
    const int*   ei  = (const int*)d_in[1];
    const int*   src = ei;
    const int*   dst = ei + NE;
    const float* W1  = (const float*)d_in[2];
    const float* g1  = (const float*)d_in[4];
    const float* be1 = (const float*)d_in[5];
    const float* W2  = (const float*)d_in[6];
    const float* g2  = (const float*)d_in[8];
    const float* be2 = (const float*)d_in[9];
    float* out = (float*)d_out;

    char* ws = (char*)d_ws;
    size_t p = 0;
    auto alloc = [&](size_t bytes) {
        size_t o = p;
        p = (p + bytes + 255) & ~(size_t)255;
        return o;
    };
    int*   zeroed  = (int*)(ws + alloc(2048));                   // cnt196 (1KB) | stats (1KB)
    int*   cnt196  = zeroed;
    float* stats   = (float*)(zeroed + 256);
    int*   bo      = (int*)(ws + alloc((size_t)(NB + 1) * 4));
    int*   cur     = (int*)(ws + alloc((size_t)NB * 4));
    int*   ebuf    = (int*)(ws + alloc((size_t)NE * 4));         // packed src|ld<<17
    int*   esrc    = (int*)(ws + alloc((size_t)NE * 4));
    int*   off     = (int*)(ws + alloc((size_t)(NN + 1) * 4));
    float* dinv    = (float*)(ws + alloc((size_t)NN * 4));
    float* A       = (float*)(ws + alloc((size_t)NN * DD * 4));  // xw staging
    float* B       = (float*)(ws + alloc((size_t)NN * DD * 4));  // raw agg
    (void)ws_size; (void)in_sizes; (void)n_in; (void)out_size;

    hipMemsetAsync(zeroed, 0, 2048, stream);

    // ---- CSR build (bucketed) overlapped with layer-1 GEMM ----
    k_l1<<<HIST_BLOCKS + GEMM_BLOCKS, 256, 0, stream>>>(x, W1, A, dst, cnt196);
    k_scanb<<<1, 256, 0, stream>>>(cnt196, bo, cur);
    k_part<<<PART_BLOCKS, 256, 0, stream>>>(src, dst, cur, ebuf);
    k_bucket<<<NB, 512, 0, stream>>>(ebuf, bo, off, dinv, esrc);

    // ---- layer 1 aggregation + stats ----
    k_agg<<<NN / 4, 256, 0, stream>>>(A, off, esrc, dinv, B);
    k_stats<<<512, 256, 0, stream>>>(B, stats, NN);

    // ---- layer 2 (BN1+leaky fused into gemm's x-load) ----
    k_gemm2<<<GEMM_BLOCKS, 256, 0, stream>>>(B, W2, A, stats, g1, be1);
    k_agg<<<NN / 4, 256, 0, stream>>>(A, off, esrc, dinv, B);
    k_stats<<<512, 256, 0, stream>>>(B, stats + 128, NN);
    k_bnact<<<1024, 256, 0, stream>>>(B, out, stats + 128, g2, be2, NN);
}

// Round 8
// 319.788 us; speedup vs baseline: 1.4069x; 1.0496x over previous
//
#include <hip/hip_runtime.h>
#include <hip/hip_bf16.h>

#define NN 100000
#define NE 1200000
#define DD 64
#define EPS 1e-5f

#define NB 196                             // ceil(NN/512) dst buckets
#define GEMM_BLOCKS (NN / 32)              // 3125
#define HIST_BLOCKS 256
#define PART_BLOCKS 256
#define EPH ((NE + HIST_BLOCKS - 1) / HIST_BLOCKS)   // 4688 edges per hist slice
#define EPB ((NE + PART_BLOCKS - 1) / PART_BLOCKS)   // 4688 edges per part slice

// ---------------- GEMM tile body: fp32 compute, bf16 output ----------------
template <bool BN>
__device__ __forceinline__ void gemm_tile(const float* __restrict__ X,
                                          const float* __restrict__ W,
                                          __hip_bfloat16* __restrict__ XWh,
                                          const float* __restrict__ stats,
                                          const float* __restrict__ gamma,
                                          const float* __restrict__ beta,
                                          int blk) {
    __shared__ float xs[32][64];
    __shared__ float sc_s[64], sh_s[64];
    int col = threadIdx.x & 63;
    int rg  = threadIdx.x >> 6;            // 0..3
    int row0 = blk * 32;

    if (BN) {
        if (threadIdx.x < 64) {
            const float inv_n = 1.0f / (float)NN;
            float mu  = stats[threadIdx.x] * inv_n;
            float var = stats[64 + threadIdx.x] * inv_n - mu * mu;
            float sc  = gamma[threadIdx.x] * rsqrtf(var + EPS);
            sc_s[threadIdx.x] = sc;
            sh_s[threadIdx.x] = beta[threadIdx.x] - sc * mu;
        }
        __syncthreads();
    }

    float w[64];
#pragma unroll
    for (int k = 0; k < 64; ++k) w[k] = W[k * 64 + col];

    for (int i = threadIdx.x; i < 32 * 16; i += 256) {
        int r = i >> 4, c4 = i & 15;
        float4 v = ((const float4*)(X + (size_t)(row0 + r) * 64))[c4];
        if (BN) {
            float4 s4 = ((const float4*)sc_s)[c4];
            float4 h4 = ((const float4*)sh_s)[c4];
            v.x = s4.x * v.x + h4.x; v.x = fmaxf(v.x, 0.01f * v.x);
            v.y = s4.y * v.y + h4.y; v.y = fmaxf(v.y, 0.01f * v.y);
            v.z = s4.z * v.z + h4.z; v.z = fmaxf(v.z, 0.01f * v.z);
            v.w = s4.w * v.w + h4.w; v.w = fmaxf(v.w, 0.01f * v.w);
        }
        ((float4*)&xs[r][0])[c4] = v;
    }
    __syncthreads();

    float acc[8];
#pragma unroll
    for (int r8 = 0; r8 < 8; ++r8) {
        int r = rg * 8 + r8;
        float a = 0.0f;
#pragma unroll
        for (int k = 0; k < 64; k += 4) {
            float4 xv = *((const float4*)&xs[r][k]);
            a += xv.x * w[k] + xv.y * w[k + 1] + xv.z * w[k + 2] + xv.w * w[k + 3];
        }
        acc[r8] = a;
    }
#pragma unroll
    for (int r8 = 0; r8 < 8; ++r8)
        XWh[(size_t)(row0 + rg * 8 + r8) * 64 + col] = __float2bfloat16(acc[r8]);
}

// ---------------- fused: coarse bucket histogram (first) + GEMM1 (after) ----------------
__global__ __launch_bounds__(256) void k_l1(const float* __restrict__ X,
                                            const float* __restrict__ W,
                                            __hip_bfloat16* __restrict__ XWh,
                                            const int* __restrict__ dst,
                                            int* __restrict__ cnt196) {
    if (blockIdx.x < HIST_BLOCKS) {
        __shared__ int h[NB];
        for (int t = threadIdx.x; t < NB; t += 256) h[t] = 0;
        __syncthreads();
        int s0 = blockIdx.x * EPH;
        int s1 = s0 + EPH; if (s1 > NE) s1 = NE;
        for (int i = s0 + threadIdx.x; i < s1; i += 256)
            atomicAdd(&h[dst[i] >> 9], 1);
        __syncthreads();
        for (int t = threadIdx.x; t < NB; t += 256)
            if (h[t]) atomicAdd(&cnt196[t], h[t]);
    } else {
        gemm_tile<false>(X, W, XWh, nullptr, nullptr, nullptr,
                         (int)blockIdx.x - HIST_BLOCKS);
    }
}

// ---------------- layer-2 GEMM with fused BN1+leaky on input ----------------
__global__ __launch_bounds__(256) void k_gemm2(const float* __restrict__ X,
                                               const float* __restrict__ W,
                                               __hip_bfloat16* __restrict__ XWh,
                                               const float* __restrict__ stats,
                                               const float* __restrict__ gamma,
                                               const float* __restrict__ beta) {
    gemm_tile<true>(X, W, XWh, stats, gamma, beta, blockIdx.x);
}

// ---------------- tiny scan of 196 bucket counts -> bucket offsets + cursors ----------------
__global__ __launch_bounds__(256) void k_scanb(const int* __restrict__ cnt196,
                                               int* __restrict__ bo,
                                               int* __restrict__ cur) {
    __shared__ int s[256];
    int t = threadIdx.x;
    int v = (t < NB) ? cnt196[t] : 0;
    s[t] = v;
    __syncthreads();
    for (int o = 1; o < 256; o <<= 1) {
        int u = (t >= o) ? s[t - o] : 0;
        __syncthreads();
        s[t] += u;
        __syncthreads();
    }
    if (t < NB) {
        int ex = s[t] - v;
        bo[t] = ex;
        cur[t] = ex;
    }
    if (t == 0) bo[NB] = NE;
}

// ---------------- partition edges into 196 dst-buckets (packed 4B records) ----------------
__global__ __launch_bounds__(256) void k_part(const int* __restrict__ src,
                                              const int* __restrict__ dst,
                                              int* __restrict__ cur,
                                              int* __restrict__ ebuf) {
    __shared__ int h[NB];
    for (int t = threadIdx.x; t < NB; t += 256) h[t] = 0;
    __syncthreads();
    int s0 = blockIdx.x * EPB;
    int s1 = s0 + EPB; if (s1 > NE) s1 = NE;
    for (int i = s0 + threadIdx.x; i < s1; i += 256)
        atomicAdd(&h[dst[i] >> 9], 1);
    __syncthreads();
    for (int t = threadIdx.x; t < NB; t += 256) {
        int c = h[t];
        h[t] = c ? atomicAdd(&cur[t], c) : 0;
    }
    __syncthreads();
    for (int i = s0 + threadIdx.x; i < s1; i += 256) {
        int d = dst[i];
        int p = atomicAdd(&h[d >> 9], 1);
        ebuf[p] = src[i] | ((d & 511) << 17);
    }
}

// ---------------- per-bucket: degrees -> dinv, local scan -> off, local fill -> esrc ----
__global__ __launch_bounds__(512) void k_bucket(const int* __restrict__ ebuf,
                                                const int* __restrict__ bo,
                                                int* __restrict__ off,
                                                float* __restrict__ dinv,
                                                int* __restrict__ esrc) {
    __shared__ int s[512];
    int b = blockIdx.x, t = threadIdx.x;
    int base = b << 9;
    int e0 = bo[b], e1 = bo[b + 1];
    s[t] = 0;
    __syncthreads();
    for (int e = e0 + t; e < e1; e += 512)
        atomicAdd(&s[ebuf[e] >> 17], 1);
    __syncthreads();
    int deg = s[t];
    if (base + t < NN) dinv[base + t] = rsqrtf((float)deg + 1.0f);
    for (int o = 1; o < 512; o <<= 1) {
        int u = (t >= o) ? s[t - o] : 0;
        __syncthreads();
        s[t] += u;
        __syncthreads();
    }
    int gstart = e0 + s[t] - deg;
    if (base + t < NN) off[base + t] = gstart;
    if (b == NB - 1 && t == 0) off[NN] = NE;
    __syncthreads();
    s[t] = gstart;
    __syncthreads();
    for (int e = e0 + t; e < e1; e += 512) {
        int v = ebuf[e];
        int p = atomicAdd(&s[v >> 17], 1);
        esrc[p] = v & 0x1FFFF;
    }
}

// ---------------- bf16x4 decode: uint2 -> 4 floats (bf16 = f32 high half) ----------------
__device__ __forceinline__ float4 bf16x4(uint2 u) {
    float4 f;
    f.x = __uint_as_float(u.x << 16);
    f.y = __uint_as_float(u.x & 0xFFFF0000u);
    f.z = __uint_as_float(u.y << 16);
    f.w = __uint_as_float(u.y & 0xFFFF0000u);
    return f;
}

// ---------------- aggregation: CSR gather over bf16 rows (128B), fp32 accum ----------------
// Wave = 1 node. 4 groups of 16 lanes; lane sub holds bf16[4] slice (uint2, 8B).
// Group g walks edges e0+g stride 4, unrolled x4 -> 16 row-gathers in flight/wave.
// out = di * (di*row_self + sum dinv[s]*row_s), written fp32.
__global__ __launch_bounds__(256) void k_agg(const __hip_bfloat16* __restrict__ XWh,
                                             const int* __restrict__ off,
                                             const int* __restrict__ esrc,
                                             const float* __restrict__ dinv,
                                             float* __restrict__ out) {
    const uint2* __restrict__ XW2 = (const uint2*)XWh;   // row = 16 uint2 = 128B
    int node = blockIdx.x * 4 + (threadIdx.x >> 6);
    int lane = threadIdx.x & 63;
    int grp  = lane >> 4;
    int sub  = lane & 15;

    float di = dinv[node];
    float sl = (grp == 0) ? di : 0.0f;
    float4 self = bf16x4(XW2[(size_t)node * 16 + sub]);
    float4 a0 = make_float4(sl * self.x, sl * self.y, sl * self.z, sl * self.w);
    float4 a1 = make_float4(0.f, 0.f, 0.f, 0.f);
    float4 a2 = make_float4(0.f, 0.f, 0.f, 0.f);
    float4 a3 = make_float4(0.f, 0.f, 0.f, 0.f);

    int e0 = off[node], e1 = off[node + 1];
    int e = e0 + grp;
    for (; e + 12 < e1; e += 16) {
        int s0 = esrc[e];
        int s1 = esrc[e + 4];
        int s2 = esrc[e + 8];
        int s3 = esrc[e + 12];
        float n0 = dinv[s0], n1 = dinv[s1], n2 = dinv[s2], n3 = dinv[s3];
        float4 r0 = bf16x4(XW2[(size_t)s0 * 16 + sub]);
        float4 r1 = bf16x4(XW2[(size_t)s1 * 16 + sub]);
        float4 r2 = bf16x4(XW2[(size_t)s2 * 16 + sub]);
        float4 r3 = bf16x4(XW2[(size_t)s3 * 16 + sub]);
        a0.x += n0 * r0.x; a0.y += n0 * r0.y; a0.z += n0 * r0.z; a0.w += n0 * r0.w;
        a1.x += n1 * r1.x; a1.y += n1 * r1.y; a1.z += n1 * r1.z; a1.w += n1 * r1.w;
        a2.x += n2 * r2.x; a2.y += n2 * r2.y; a2.z += n2 * r2.z; a2.w += n2 * r2.w;
        a3.x += n3 * r3.x; a3.y += n3 * r3.y; a3.z += n3 * r3.z; a3.w += n3 * r3.w;
    }
    for (; e < e1; e += 4) {
        int s = esrc[e];
        float n = dinv[s];
        float4 r = bf16x4(XW2[(size_t)s * 16 + sub]);
        a0.x += n * r.x; a0.y += n * r.y; a0.z += n * r.z; a0.w += n * r.w;
    }
    a0.x += a1.x + a2.x + a3.x;
    a0.y += a1.y + a2.y + a3.y;
    a0.z += a1.z + a2.z + a3.z;
    a0.w += a1.w + a2.w + a3.w;

#pragma unroll
    for (int m = 16; m <= 32; m <<= 1) {
        a0.x += __shfl_xor(a0.x, m);
        a0.y += __shfl_xor(a0.y, m);
        a0.z += __shfl_xor(a0.z, m);
        a0.w += __shfl_xor(a0.w, m);
    }
    if (grp == 0) {
        a0.x *= di; a0.y *= di; a0.z *= di; a0.w *= di;
        ((float4*)out)[(size_t)node * 16 + sub] = a0;
    }
}

// ---------------- BN stats: column sums and sumsq ----------------
__global__ __launch_bounds__(256) void k_stats(const float* __restrict__ X,
                                               float* __restrict__ stats, int n) {
    __shared__ float ls[4][64], lq[4][64];
    int lane = threadIdx.x & 63, rg = threadIdx.x >> 6;
    float s = 0.0f, sq = 0.0f;
    for (int r = blockIdx.x * 4 + rg; r < n; r += gridDim.x * 4) {
        float v = X[(size_t)r * 64 + lane];
        s += v; sq += v * v;
    }
    ls[rg][lane] = s; lq[rg][lane] = sq;
    __syncthreads();
    if (rg == 0) {
        s  = ls[0][lane] + ls[1][lane] + ls[2][lane] + ls[3][lane];
        sq = lq[0][lane] + lq[1][lane] + lq[2][lane] + lq[3][lane];
        atomicAdd(&stats[lane], s);
        atomicAdd(&stats[64 + lane], sq);
    }
}

// ---------------- BN apply + leaky_relu (out-of-place) ----------------
__global__ __launch_bounds__(256) void k_bnact(const float* __restrict__ X,
                                               float* __restrict__ Y,
                                               const float* __restrict__ stats,
                                               const float* __restrict__ gamma,
                                               const float* __restrict__ beta,
                                               int n) {
    int lane = threadIdx.x & 63, rg = threadIdx.x >> 6;
    float inv_n = 1.0f / (float)n;
    float mu  = stats[lane] * inv_n;
    float var = stats[64 + lane] * inv_n - mu * mu;
    float sc  = gamma[lane] * rsqrtf(var + EPS);
    float sh  = beta[lane] - sc * mu;
    for (int r = blockIdx.x * 4 + rg; r < n; r += gridDim.x * 4) {
        float v = X[(size_t)r * 64 + lane];
        v = sc * v + sh;
        Y[(size_t)r * 64 + lane] = fmaxf(v, 0.01f * v);
    }
}

extern "C" void kernel_launch(void* const* d_in, const int* in_sizes, int n_in,
                              void* d_out, int out_size, void* d_ws, size_t ws_size,
                              hipStream_t stream) {
    const float* x   = (const float*)d_in[0];
    const int*   ei  = (const int*)d_in[1];
    const int*   src = ei;
    const int*   dst = ei + NE;
    const float* W1  = (const float*)d_in[2];
    const float* g1  = (const float*)d_in[4];
    const float* be1 = (const float*)d_in[5];
    const float* W2  = (const float*)d_in[6];
    const float* g2  = (const float*)d_in[8];
    const float* be2 = (const float*)d_in[9];
    float* out = (float*)d_out;

    char* ws = (char*)d_ws;
    size_t p = 0;
    auto alloc = [&](size_t bytes) {
        size_t o = p;
        p = (p + bytes + 255) & ~(size_t)255;
        return o;
    };
    int*   zeroed  = (int*)(ws + alloc(2048));                   // cnt196 | stats
    int*   cnt196  = zeroed;
    float* stats   = (float*)(zeroed + 256);
    int*   bo      = (int*)(ws + alloc((size_t)(NB + 1) * 4));
    int*   cur     = (int*)(ws + alloc((size_t)NB * 4));
    int*   ebuf    = (int*)(ws + alloc((size_t)NE * 4));         // packed src|ld<<17
    int*   esrc    = (int*)(ws + alloc((size_t)NE * 4));
    int*   off     = (int*)(ws + alloc((size_t)(NN + 1) * 4));
    float* dinv    = (float*)(ws + alloc((size_t)NN * 4));
    __hip_bfloat16* Ah = (__hip_bfloat16*)(ws + alloc((size_t)NN * DD * 2)); // xw bf16
    float* B       = (float*)(ws + alloc((size_t)NN * DD * 4)); // raw agg fp32
    (void)ws_size; (void)in_sizes; (void)n_in; (void)out_size;

    hipMemsetAsync(zeroed, 0, 2048, stream);

    // ---- CSR build (bucketed) overlapped with layer-1 GEMM ----
    k_l1<<<HIST_BLOCKS + GEMM_BLOCKS, 256, 0, stream>>>(x, W1, Ah, dst, cnt196);
    k_scanb<<<1, 256, 0, stream>>>(cnt196, bo, cur);
    k_part<<<PART_BLOCKS, 256, 0, stream>>>(src, dst, cur, ebuf);
    k_bucket<<<NB, 512, 0, stream>>>(ebuf, bo, off, dinv, esrc);

    // ---- layer 1 aggregation + stats ----
    k_agg<<<NN / 4, 256, 0, stream>>>(Ah, off, esrc, dinv, B);
    k_stats<<<512, 256, 0, stream>>>(B, stats, NN);

    // ---- layer 2 (BN1+leaky fused into gemm's x-load) ----
    k_gemm2<<<GEMM_BLOCKS, 256, 0, stream>>>(B, W2, Ah, stats, g1, be1);
    k_agg<<<NN / 4, 256, 0, stream>>>(Ah, off, esrc, dinv, B);
    k_stats<<<512, 256, 0, stream>>>(B, stats + 128, NN);
    k_bnact<<<1024, 256, 0, stream>>>(B, out, stats + 128, g2, be2, NN);
}

// Round 9
// 288.446 us; speedup vs baseline: 1.5598x; 1.1087x over previous
//
#include <hip/hip_runtime.h>
#include <hip/hip_bf16.h>

#define NN 100000
#define NE 1200000
#define DD 64
#define EPS 1e-5f

#define NB 196                             // ceil(NN/512) dst buckets
#define GEMM_BLOCKS (NN / 32)              // 3125
#define HIST_BLOCKS 256
#define PART_BLOCKS 256
#define EPH ((NE + HIST_BLOCKS - 1) / HIST_BLOCKS)   // 4688 edges per hist slice
#define EPB ((NE + PART_BLOCKS - 1) / PART_BLOCKS)   // 4688 edges per part slice

// ---------------- GEMM tile body: fp32 compute, bf16 output ----------------
template <bool BN>
__device__ __forceinline__ void gemm_tile(const float* __restrict__ X,
                                          const float* __restrict__ W,
                                          __hip_bfloat16* __restrict__ XWh,
                                          const float* __restrict__ stats,
                                          const float* __restrict__ gamma,
                                          const float* __restrict__ beta,
                                          int blk) {
    __shared__ float xs[32][64];
    __shared__ float sc_s[64], sh_s[64];
    int col = threadIdx.x & 63;
    int rg  = threadIdx.x >> 6;            // 0..3
    int row0 = blk * 32;

    if (BN) {
        if (threadIdx.x < 64) {
            const float inv_n = 1.0f / (float)NN;
            float mu  = stats[threadIdx.x] * inv_n;
            float var = stats[64 + threadIdx.x] * inv_n - mu * mu;
            float sc  = gamma[threadIdx.x] * rsqrtf(var + EPS);
            sc_s[threadIdx.x] = sc;
            sh_s[threadIdx.x] = beta[threadIdx.x] - sc * mu;
        }
        __syncthreads();
    }

    float w[64];
#pragma unroll
    for (int k = 0; k < 64; ++k) w[k] = W[k * 64 + col];

    for (int i = threadIdx.x; i < 32 * 16; i += 256) {
        int r = i >> 4, c4 = i & 15;
        float4 v = ((const float4*)(X + (size_t)(row0 + r) * 64))[c4];
        if (BN) {
            float4 s4 = ((const float4*)sc_s)[c4];
            float4 h4 = ((const float4*)sh_s)[c4];
            v.x = s4.x * v.x + h4.x; v.x = fmaxf(v.x, 0.01f * v.x);
            v.y = s4.y * v.y + h4.y; v.y = fmaxf(v.y, 0.01f * v.y);
            v.z = s4.z * v.z + h4.z; v.z = fmaxf(v.z, 0.01f * v.z);
            v.w = s4.w * v.w + h4.w; v.w = fmaxf(v.w, 0.01f * v.w);
        }
        ((float4*)&xs[r][0])[c4] = v;
    }
    __syncthreads();

    float acc[8];
#pragma unroll
    for (int r8 = 0; r8 < 8; ++r8) {
        int r = rg * 8 + r8;
        float a = 0.0f;
#pragma unroll
        for (int k = 0; k < 64; k += 4) {
            float4 xv = *((const float4*)&xs[r][k]);
            a += xv.x * w[k] + xv.y * w[k + 1] + xv.z * w[k + 2] + xv.w * w[k + 3];
        }
        acc[r8] = a;
    }
#pragma unroll
    for (int r8 = 0; r8 < 8; ++r8)
        XWh[(size_t)(row0 + rg * 8 + r8) * 64 + col] = __float2bfloat16(acc[r8]);
}

// ---------------- fused: coarse bucket histogram (first) + GEMM1 (after) ----------------
__global__ __launch_bounds__(256) void k_l1(const float* __restrict__ X,
                                            const float* __restrict__ W,
                                            __hip_bfloat16* __restrict__ XWh,
                                            const int* __restrict__ dst,
                                            int* __restrict__ cnt196) {
    if (blockIdx.x < HIST_BLOCKS) {
        __shared__ int h[NB];
        for (int t = threadIdx.x; t < NB; t += 256) h[t] = 0;
        __syncthreads();
        int s0 = blockIdx.x * EPH;
        int s1 = s0 + EPH; if (s1 > NE) s1 = NE;
        for (int i = s0 + threadIdx.x; i < s1; i += 256)
            atomicAdd(&h[dst[i] >> 9], 1);
        __syncthreads();
        for (int t = threadIdx.x; t < NB; t += 256)
            if (h[t]) atomicAdd(&cnt196[t], h[t]);
    } else {
        gemm_tile<false>(X, W, XWh, nullptr, nullptr, nullptr,
                         (int)blockIdx.x - HIST_BLOCKS);
    }
}

// ---------------- layer-2 GEMM with fused BN1+leaky on input ----------------
__global__ __launch_bounds__(256) void k_gemm2(const float* __restrict__ X,
                                               const float* __restrict__ W,
                                               __hip_bfloat16* __restrict__ XWh,
                                               const float* __restrict__ stats,
                                               const float* __restrict__ gamma,
                                               const float* __restrict__ beta) {
    gemm_tile<true>(X, W, XWh, stats, gamma, beta, blockIdx.x);
}

// ---------------- tiny scan of 196 bucket counts -> bucket offsets + cursors ----------------
__global__ __launch_bounds__(256) void k_scanb(const int* __restrict__ cnt196,
                                               int* __restrict__ bo,
                                               int* __restrict__ cur) {
    __shared__ int s[256];
    int t = threadIdx.x;
    int v = (t < NB) ? cnt196[t] : 0;
    s[t] = v;
    __syncthreads();
    for (int o = 1; o < 256; o <<= 1) {
        int u = (t >= o) ? s[t - o] : 0;
        __syncthreads();
        s[t] += u;
        __syncthreads();
    }
    if (t < NB) {
        int ex = s[t] - v;
        bo[t] = ex;
        cur[t] = ex;
    }
    if (t == 0) bo[NB] = NE;
}

// ---------------- partition edges into 196 dst-buckets (packed 4B records) ----------------
__global__ __launch_bounds__(256) void k_part(const int* __restrict__ src,
                                              const int* __restrict__ dst,
                                              int* __restrict__ cur,
                                              int* __restrict__ ebuf) {
    __shared__ int h[NB];
    for (int t = threadIdx.x; t < NB; t += 256) h[t] = 0;
    __syncthreads();
    int s0 = blockIdx.x * EPB;
    int s1 = s0 + EPB; if (s1 > NE) s1 = NE;
    for (int i = s0 + threadIdx.x; i < s1; i += 256)
        atomicAdd(&h[dst[i] >> 9], 1);
    __syncthreads();
    for (int t = threadIdx.x; t < NB; t += 256) {
        int c = h[t];
        h[t] = c ? atomicAdd(&cur[t], c) : 0;
    }
    __syncthreads();
    for (int i = s0 + threadIdx.x; i < s1; i += 256) {
        int d = dst[i];
        int p = atomicAdd(&h[d >> 9], 1);
        ebuf[p] = src[i] | ((d & 511) << 17);
    }
}

// ---------------- per-bucket: degrees -> dinv, local scan -> off, local fill -> esrc ----
__global__ __launch_bounds__(512) void k_bucket(const int* __restrict__ ebuf,
                                                const int* __restrict__ bo,
                                                int* __restrict__ off,
                                                float* __restrict__ dinv,
                                                int* __restrict__ esrc) {
    __shared__ int s[512];
    int b = blockIdx.x, t = threadIdx.x;
    int base = b << 9;
    int e0 = bo[b], e1 = bo[b + 1];
    s[t] = 0;
    __syncthreads();
    for (int e = e0 + t; e < e1; e += 512)
        atomicAdd(&s[ebuf[e] >> 17], 1);
    __syncthreads();
    int deg = s[t];
    if (base + t < NN) dinv[base + t] = rsqrtf((float)deg + 1.0f);
    for (int o = 1; o < 512; o <<= 1) {
        int u = (t >= o) ? s[t - o] : 0;
        __syncthreads();
        s[t] += u;
        __syncthreads();
    }
    int gstart = e0 + s[t] - deg;
    if (base + t < NN) off[base + t] = gstart;
    if (b == NB - 1 && t == 0) off[NN] = NE;
    __syncthreads();
    s[t] = gstart;
    __syncthreads();
    for (int e = e0 + t; e < e1; e += 512) {
        int v = ebuf[e];
        int p = atomicAdd(&s[v >> 17], 1);
        esrc[p] = v & 0x1FFFF;
    }
}

// ---------------- decode 8 bf16 (uint4) -> 8 fp32 ----------------
__device__ __forceinline__ void bf16x8(uint4 u, float* f) {
    f[0] = __uint_as_float(u.x << 16);
    f[1] = __uint_as_float(u.x & 0xFFFF0000u);
    f[2] = __uint_as_float(u.y << 16);
    f[3] = __uint_as_float(u.y & 0xFFFF0000u);
    f[4] = __uint_as_float(u.z << 16);
    f[5] = __uint_as_float(u.z & 0xFFFF0000u);
    f[6] = __uint_as_float(u.w << 16);
    f[7] = __uint_as_float(u.w & 0xFFFF0000u);
}

// ---------------- aggregation v3: team-per-node ----------------
// 8-lane team owns one node; lane sub holds cols [sub*8, sub*8+8) as uint4 (16B bf16).
// Team walks its edge list serially, 2x unrolled with dual accumulators ->
// ~16 independent 128B row-gathers in flight per wave (8 teams x 2).
// out = di * (di*row_self + sum dinv[s]*row_s), fp32.
__global__ __launch_bounds__(256) void k_agg(const __hip_bfloat16* __restrict__ XWh,
                                             const int* __restrict__ off,
                                             const int* __restrict__ esrc,
                                             const float* __restrict__ dinv,
                                             float* __restrict__ out) {
    const uint4* __restrict__ XW4 = (const uint4*)XWh;   // row = 8 uint4 = 128B
    int team = threadIdx.x >> 3;                         // 0..31
    int sub  = threadIdx.x & 7;
    int node = blockIdx.x * 32 + team;

    float di = dinv[node];
    float a[8], b[8], r0[8], r1[8];
    uint4 us = XW4[(size_t)node * 8 + sub];
    bf16x8(us, a);
#pragma unroll
    for (int i = 0; i < 8; ++i) { a[i] *= di; b[i] = 0.0f; }

    int e0 = off[node], e1 = off[node + 1];
    int e = e0;
    for (; e + 1 < e1; e += 2) {
        int s0 = esrc[e];
        int s1 = esrc[e + 1];
        float n0 = dinv[s0], n1 = dinv[s1];
        uint4 u0 = XW4[(size_t)s0 * 8 + sub];
        uint4 u1 = XW4[(size_t)s1 * 8 + sub];
        bf16x8(u0, r0);
        bf16x8(u1, r1);
#pragma unroll
        for (int i = 0; i < 8; ++i) a[i] += n0 * r0[i];
#pragma unroll
        for (int i = 0; i < 8; ++i) b[i] += n1 * r1[i];
    }
    if (e < e1) {
        int s0 = esrc[e];
        float n0 = dinv[s0];
        uint4 u0 = XW4[(size_t)s0 * 8 + sub];
        bf16x8(u0, r0);
#pragma unroll
        for (int i = 0; i < 8; ++i) a[i] += n0 * r0[i];
    }
#pragma unroll
    for (int i = 0; i < 8; ++i) a[i] = (a[i] + b[i]) * di;

    float4* o4 = (float4*)out;
    o4[(size_t)node * 16 + sub * 2]     = make_float4(a[0], a[1], a[2], a[3]);
    o4[(size_t)node * 16 + sub * 2 + 1] = make_float4(a[4], a[5], a[6], a[7]);
}

// ---------------- BN stats: column sums and sumsq ----------------
__global__ __launch_bounds__(256) void k_stats(const float* __restrict__ X,
                                               float* __restrict__ stats, int n) {
    __shared__ float ls[4][64], lq[4][64];
    int lane = threadIdx.x & 63, rg = threadIdx.x >> 6;
    float s = 0.0f, sq = 0.0f;
    for (int r = blockIdx.x * 4 + rg; r < n; r += gridDim.x * 4) {
        float v = X[(size_t)r * 64 + lane];
        s += v; sq += v * v;
    }
    ls[rg][lane] = s; lq[rg][lane] = sq;
    __syncthreads();
    if (rg == 0) {
        s  = ls[0][lane] + ls[1][lane] + ls[2][lane] + ls[3][lane];
        sq = lq[0][lane] + lq[1][lane] + lq[2][lane] + lq[3][lane];
        atomicAdd(&stats[lane], s);
        atomicAdd(&stats[64 + lane], sq);
    }
}

// ---------------- BN apply + leaky_relu (out-of-place) ----------------
__global__ __launch_bounds__(256) void k_bnact(const float* __restrict__ X,
                                               float* __restrict__ Y,
                                               const float* __restrict__ stats,
                                               const float* __restrict__ gamma,
                                               const float* __restrict__ beta,
                                               int n) {
    int lane = threadIdx.x & 63, rg = threadIdx.x >> 6;
    float inv_n = 1.0f / (float)n;
    float mu  = stats[lane] * inv_n;
    float var = stats[64 + lane] * inv_n - mu * mu;
    float sc  = gamma[lane] * rsqrtf(var + EPS);
    float sh  = beta[lane] - sc * mu;
    for (int r = blockIdx.x * 4 + rg; r < n; r += gridDim.x * 4) {
        float v = X[(size_t)r * 64 + lane];
        v = sc * v + sh;
        Y[(size_t)r * 64 + lane] = fmaxf(v, 0.01f * v);
    }
}

extern "C" void kernel_launch(void* const* d_in, const int* in_sizes, int n_in,
                              void* d_out, int out_size, void* d_ws, size_t ws_size,
                              hipStream_t stream) {
    const float* x   = (const float*)d_in[0];
    const int*   ei  = (const int*)d_in[1];
    const int*   src = ei;
    const int*   dst = ei + NE;
    const float* W1  = (const float*)d_in[2];
    const float* g1  = (const float*)d_in[4];
    const float* be1 = (const float*)d_in[5];
    const float* W2  = (const float*)d_in[6];
    const float* g2  = (const float*)d_in[8];
    const float* be2 = (const float*)d_in[9];
    float* out = (float*)d_out;

    char* ws = (char*)d_ws;
    size_t p = 0;
    auto alloc = [&](size_t bytes) {
        size_t o = p;
        p = (p + bytes + 255) & ~(size_t)255;
        return o;
    };
    int*   zeroed  = (int*)(ws + alloc(2048));                   // cnt196 | stats
    int*   cnt196  = zeroed;
    float* stats   = (float*)(zeroed + 256);
    int*   bo      = (int*)(ws + alloc((size_t)(NB + 1) * 4));
    int*   cur     = (int*)(ws + alloc((size_t)NB * 4));
    int*   ebuf    = (int*)(ws + alloc((size_t)NE * 4));         // packed src|ld<<17
    int*   esrc    = (int*)(ws + alloc((size_t)NE * 4));
    int*   off     = (int*)(ws + alloc((size_t)(NN + 1) * 4));
    float* dinv    = (float*)(ws + alloc((size_t)NN * 4));
    __hip_bfloat16* Ah = (__hip_bfloat16*)(ws + alloc((size_t)NN * DD * 2)); // xw bf16
    float* B       = (float*)(ws + alloc((size_t)NN * DD * 4)); // raw agg fp32
    (void)ws_size; (void)in_sizes; (void)n_in; (void)out_size;

    hipMemsetAsync(zeroed, 0, 2048, stream);

    // ---- CSR build (bucketed) overlapped with layer-1 GEMM ----
    k_l1<<<HIST_BLOCKS + GEMM_BLOCKS, 256, 0, stream>>>(x, W1, Ah, dst, cnt196);
    k_scanb<<<1, 256, 0, stream>>>(cnt196, bo, cur);
    k_part<<<PART_BLOCKS, 256, 0, stream>>>(src, dst, cur, ebuf);
    k_bucket<<<NB, 512, 0, stream>>>(ebuf, bo, off, dinv, esrc);

    // ---- layer 1 aggregation + stats ----
    k_agg<<<NN / 32, 256, 0, stream>>>(Ah, off, esrc, dinv, B);
    k_stats<<<512, 256, 0, stream>>>(B, stats, NN);

    // ---- layer 2 (BN1+leaky fused into gemm's x-load) ----
    k_gemm2<<<GEMM_BLOCKS, 256, 0, stream>>>(B, W2, Ah, stats, g1, be1);
    k_agg<<<NN / 32, 256, 0, stream>>>(Ah, off, esrc, dinv, B);
    k_stats<<<512, 256, 0, stream>>>(B, stats + 128, NN);
    k_bnact<<<1024, 256, 0, stream>>>(B, out, stats + 128, g2, be2, NN);
}

// Round 10
// 282.644 us; speedup vs baseline: 1.5918x; 1.0205x over previous
//
#include <hip/hip_runtime.h>
#include <hip/hip_bf16.h>

#define NN 100000
#define NE 1200000
#define DD 64
#define EPS 1e-5f

#define NB 196                             // ceil(NN/512) dst buckets
#define GEMM_BLOCKS (NN / 32)              // 3125
#define HIST_BLOCKS 256
#define PART_BLOCKS 256
#define EPH ((NE + HIST_BLOCKS - 1) / HIST_BLOCKS)   // 4688 edges per hist slice
#define EPB ((NE + PART_BLOCKS - 1) / PART_BLOCKS)   // 4688 edges per part slice

// ---------------- GEMM tile body: fp32 compute, bf16 output ----------------
template <bool BN>
__device__ __forceinline__ void gemm_tile(const float* __restrict__ X,
                                          const float* __restrict__ W,
                                          __hip_bfloat16* __restrict__ XWh,
                                          const float* __restrict__ stats,
                                          const float* __restrict__ gamma,
                                          const float* __restrict__ beta,
                                          int blk) {
    __shared__ float xs[32][64];
    __shared__ float sc_s[64], sh_s[64];
    int col = threadIdx.x & 63;
    int rg  = threadIdx.x >> 6;            // 0..3
    int row0 = blk * 32;

    if (BN) {
        if (threadIdx.x < 64) {
            const float inv_n = 1.0f / (float)NN;
            float mu  = stats[threadIdx.x] * inv_n;
            float var = stats[64 + threadIdx.x] * inv_n - mu * mu;
            float sc  = gamma[threadIdx.x] * rsqrtf(var + EPS);
            sc_s[threadIdx.x] = sc;
            sh_s[threadIdx.x] = beta[threadIdx.x] - sc * mu;
        }
        __syncthreads();
    }

    float w[64];
#pragma unroll
    for (int k = 0; k < 64; ++k) w[k] = W[k * 64 + col];

    for (int i = threadIdx.x; i < 32 * 16; i += 256) {
        int r = i >> 4, c4 = i & 15;
        float4 v = ((const float4*)(X + (size_t)(row0 + r) * 64))[c4];
        if (BN) {
            float4 s4 = ((const float4*)sc_s)[c4];
            float4 h4 = ((const float4*)sh_s)[c4];
            v.x = s4.x * v.x + h4.x; v.x = fmaxf(v.x, 0.01f * v.x);
            v.y = s4.y * v.y + h4.y; v.y = fmaxf(v.y, 0.01f * v.y);
            v.z = s4.z * v.z + h4.z; v.z = fmaxf(v.z, 0.01f * v.z);
            v.w = s4.w * v.w + h4.w; v.w = fmaxf(v.w, 0.01f * v.w);
        }
        ((float4*)&xs[r][0])[c4] = v;
    }
    __syncthreads();

    float acc[8];
#pragma unroll
    for (int r8 = 0; r8 < 8; ++r8) {
        int r = rg * 8 + r8;
        float a = 0.0f;
#pragma unroll
        for (int k = 0; k < 64; k += 4) {
            float4 xv = *((const float4*)&xs[r][k]);
            a += xv.x * w[k] + xv.y * w[k + 1] + xv.z * w[k + 2] + xv.w * w[k + 3];
        }
        acc[r8] = a;
    }
#pragma unroll
    for (int r8 = 0; r8 < 8; ++r8)
        XWh[(size_t)(row0 + rg * 8 + r8) * 64 + col] = __float2bfloat16(acc[r8]);
}

// ---------------- coarse bucket histogram (standalone, runs before scanb) ---------
__global__ __launch_bounds__(256) void k_hist(const int* __restrict__ dst,
                                              int* __restrict__ cnt196) {
    __shared__ int h[NB];
    for (int t = threadIdx.x; t < NB; t += 256) h[t] = 0;
    __syncthreads();
    int s0 = blockIdx.x * EPH;
    int s1 = s0 + EPH; if (s1 > NE) s1 = NE;
    for (int i = s0 + threadIdx.x; i < s1; i += 256)
        atomicAdd(&h[dst[i] >> 9], 1);
    __syncthreads();
    for (int t = threadIdx.x; t < NB; t += 256)
        if (h[t]) atomicAdd(&cnt196[t], h[t]);
}

// ---------------- tiny scan of 196 bucket counts -> bucket offsets + cursors -----
__global__ __launch_bounds__(256) void k_scanb(const int* __restrict__ cnt196,
                                               int* __restrict__ bo,
                                               int* __restrict__ cur) {
    __shared__ int s[256];
    int t = threadIdx.x;
    int v = (t < NB) ? cnt196[t] : 0;
    s[t] = v;
    __syncthreads();
    for (int o = 1; o < 256; o <<= 1) {
        int u = (t >= o) ? s[t - o] : 0;
        __syncthreads();
        s[t] += u;
        __syncthreads();
    }
    if (t < NB) {
        int ex = s[t] - v;
        bo[t] = ex;
        cur[t] = ex;
    }
    if (t == 0) bo[NB] = NE;
}

// ---------------- fused: edge partition (first 256 blocks) + GEMM1 (rest) --------
// Part's latency-bound LDS/global-atomic work overlaps gemm's VALU work.
__global__ __launch_bounds__(256) void k_pg(const float* __restrict__ X,
                                            const float* __restrict__ W,
                                            __hip_bfloat16* __restrict__ XWh,
                                            const int* __restrict__ src,
                                            const int* __restrict__ dst,
                                            int* __restrict__ cur,
                                            int* __restrict__ ebuf) {
    if (blockIdx.x < PART_BLOCKS) {
        __shared__ int h[NB];
        for (int t = threadIdx.x; t < NB; t += 256) h[t] = 0;
        __syncthreads();
        int s0 = blockIdx.x * EPB;
        int s1 = s0 + EPB; if (s1 > NE) s1 = NE;
        for (int i = s0 + threadIdx.x; i < s1; i += 256)
            atomicAdd(&h[dst[i] >> 9], 1);
        __syncthreads();
        for (int t = threadIdx.x; t < NB; t += 256) {
            int c = h[t];
            h[t] = c ? atomicAdd(&cur[t], c) : 0;
        }
        __syncthreads();
        for (int i = s0 + threadIdx.x; i < s1; i += 256) {
            int d = dst[i];
            int p = atomicAdd(&h[d >> 9], 1);
            ebuf[p] = src[i] | ((d & 511) << 17);
        }
    } else {
        gemm_tile<false>(X, W, XWh, nullptr, nullptr, nullptr,
                         (int)blockIdx.x - PART_BLOCKS);
    }
}

// ---------------- layer-2 GEMM with fused BN1+leaky on input ----------------
__global__ __launch_bounds__(256) void k_gemm2(const float* __restrict__ X,
                                               const float* __restrict__ W,
                                               __hip_bfloat16* __restrict__ XWh,
                                               const float* __restrict__ stats,
                                               const float* __restrict__ gamma,
                                               const float* __restrict__ beta) {
    gemm_tile<true>(X, W, XWh, stats, gamma, beta, blockIdx.x);
}

// ---------------- per-bucket: degrees -> dinv, local scan -> off, local fill -----
__global__ __launch_bounds__(512) void k_bucket(const int* __restrict__ ebuf,
                                                const int* __restrict__ bo,
                                                int* __restrict__ off,
                                                float* __restrict__ dinv,
                                                int* __restrict__ esrc) {
    __shared__ int s[512];
    int b = blockIdx.x, t = threadIdx.x;
    int base = b << 9;
    int e0 = bo[b], e1 = bo[b + 1];
    s[t] = 0;
    __syncthreads();
    for (int e = e0 + t; e < e1; e += 512)
        atomicAdd(&s[ebuf[e] >> 17], 1);
    __syncthreads();
    int deg = s[t];
    if (base + t < NN) dinv[base + t] = rsqrtf((float)deg + 1.0f);
    for (int o = 1; o < 512; o <<= 1) {
        int u = (t >= o) ? s[t - o] : 0;
        __syncthreads();
        s[t] += u;
        __syncthreads();
    }
    int gstart = e0 + s[t] - deg;
    if (base + t < NN) off[base + t] = gstart;
    if (b == NB - 1 && t == 0) off[NN] = NE;
    __syncthreads();
    s[t] = gstart;
    __syncthreads();
    for (int e = e0 + t; e < e1; e += 512) {
        int v = ebuf[e];
        int p = atomicAdd(&s[v >> 17], 1);
        esrc[p] = v & 0x1FFFF;
    }
}

// ---------------- decode 8 bf16 (uint4) -> 8 fp32 ----------------
__device__ __forceinline__ void bf16x8(uint4 u, float* f) {
    f[0] = __uint_as_float(u.x << 16);
    f[1] = __uint_as_float(u.x & 0xFFFF0000u);
    f[2] = __uint_as_float(u.y << 16);
    f[3] = __uint_as_float(u.y & 0xFFFF0000u);
    f[4] = __uint_as_float(u.z << 16);
    f[5] = __uint_as_float(u.z & 0xFFFF0000u);
    f[6] = __uint_as_float(u.w << 16);
    f[7] = __uint_as_float(u.w & 0xFFFF0000u);
}

// ---------------- aggregation: team-per-node, 4-deep unroll ----------------
// 8-lane team owns one node; lane sub holds cols [sub*8, sub*8+8) as uint4 (16B bf16).
// 4 accumulators -> up to 32 independent 128B row-gathers in flight per wave.
// out = di * (di*row_self + sum dinv[s]*row_s), fp32.
__global__ __launch_bounds__(256) void k_agg(const __hip_bfloat16* __restrict__ XWh,
                                             const int* __restrict__ off,
                                             const int* __restrict__ esrc,
                                             const float* __restrict__ dinv,
                                             float* __restrict__ out) {
    const uint4* __restrict__ XW4 = (const uint4*)XWh;   // row = 8 uint4 = 128B
    int team = threadIdx.x >> 3;                         // 0..31
    int sub  = threadIdx.x & 7;
    int node = blockIdx.x * 32 + team;

    float di = dinv[node];
    float a[8], b[8], c[8], d[8], r0[8], r1[8], r2[8], r3[8];
    uint4 us = XW4[(size_t)node * 8 + sub];
    bf16x8(us, a);
#pragma unroll
    for (int i = 0; i < 8; ++i) { a[i] *= di; b[i] = 0.0f; c[i] = 0.0f; d[i] = 0.0f; }

    int e0 = off[node], e1 = off[node + 1];
    int e = e0;
    for (; e + 3 < e1; e += 4) {
        int s0 = esrc[e];
        int s1 = esrc[e + 1];
        int s2 = esrc[e + 2];
        int s3 = esrc[e + 3];
        float n0 = dinv[s0], n1 = dinv[s1], n2 = dinv[s2], n3 = dinv[s3];
        uint4 u0 = XW4[(size_t)s0 * 8 + sub];
        uint4 u1 = XW4[(size_t)s1 * 8 + sub];
        uint4 u2 = XW4[(size_t)s2 * 8 + sub];
        uint4 u3 = XW4[(size_t)s3 * 8 + sub];
        bf16x8(u0, r0);
        bf16x8(u1, r1);
        bf16x8(u2, r2);
        bf16x8(u3, r3);
#pragma unroll
        for (int i = 0; i < 8; ++i) a[i] += n0 * r0[i];
#pragma unroll
        for (int i = 0; i < 8; ++i) b[i] += n1 * r1[i];
#pragma unroll
        for (int i = 0; i < 8; ++i) c[i] += n2 * r2[i];
#pragma unroll
        for (int i = 0; i < 8; ++i) d[i] += n3 * r3[i];
    }
    for (; e < e1; ++e) {
        int s0 = esrc[e];
        float n0 = dinv[s0];
        uint4 u0 = XW4[(size_t)s0 * 8 + sub];
        bf16x8(u0, r0);
#pragma unroll
        for (int i = 0; i < 8; ++i) a[i] += n0 * r0[i];
    }
#pragma unroll
    for (int i = 0; i < 8; ++i) a[i] = ((a[i] + b[i]) + (c[i] + d[i])) * di;

    float4* o4 = (float4*)out;
    o4[(size_t)node * 16 + sub * 2]     = make_float4(a[0], a[1], a[2], a[3]);
    o4[(size_t)node * 16 + sub * 2 + 1] = make_float4(a[4], a[5], a[6], a[7]);
}

// ---------------- BN stats: column sums and sumsq ----------------
__global__ __launch_bounds__(256) void k_stats(const float* __restrict__ X,
                                               float* __restrict__ stats, int n) {
    __shared__ float ls[4][64], lq[4][64];
    int lane = threadIdx.x & 63, rg = threadIdx.x >> 6;
    float s = 0.0f, sq = 0.0f;
    for (int r = blockIdx.x * 4 + rg; r < n; r += gridDim.x * 4) {
        float v = X[(size_t)r * 64 + lane];
        s += v; sq += v * v;
    }
    ls[rg][lane] = s; lq[rg][lane] = sq;
    __syncthreads();
    if (rg == 0) {
        s  = ls[0][lane] + ls[1][lane] + ls[2][lane] + ls[3][lane];
        sq = lq[0][lane] + lq[1][lane] + lq[2][lane] + lq[3][lane];
        atomicAdd(&stats[lane], s);
        atomicAdd(&stats[64 + lane], sq);
    }
}

// ---------------- BN apply + leaky_relu (out-of-place) ----------------
__global__ __launch_bounds__(256) void k_bnact(const float* __restrict__ X,
                                               float* __restrict__ Y,
                                               const float* __restrict__ stats,
                                               const float* __restrict__ gamma,
                                               const float* __restrict__ beta,
                                               int n) {
    int lane = threadIdx.x & 63, rg = threadIdx.x >> 6;
    float inv_n = 1.0f / (float)n;
    float mu  = stats[lane] * inv_n;
    float var = stats[64 + lane] * inv_n - mu * mu;
    float sc  = gamma[lane] * rsqrtf(var + EPS);
    float sh  = beta[lane] - sc * mu;
    for (int r = blockIdx.x * 4 + rg; r < n; r += gridDim.x * 4) {
        float v = X[(size_t)r * 64 + lane];
        v = sc * v + sh;
        Y[(size_t)r * 64 + lane] = fmaxf(v, 0.01f * v);
    }
}

extern "C" void kernel_launch(void* const* d_in, const int* in_sizes, int n_in,
                              void* d_out, int out_size, void* d_ws, size_t ws_size,
                              hipStream_t stream) {
    const float* x   = (const float*)d_in[0];
    const int*   ei  = (const int*)d_in[1];
    const int*   src = ei;
    const int*   dst = ei + NE;
    const float* W1  = (const float*)d_in[2];
    const float* g1  = (const float*)d_in[4];
    const float* be1 = (const float*)d_in[5];
    const float* W2  = (const float*)d_in[6];
    const float* g2  = (const float*)d_in[8];
    const float* be2 = (const float*)d_in[9];
    float* out = (float*)d_out;

    char* ws = (char*)d_ws;
    size_t p = 0;
    auto alloc = [&](size_t bytes) {
        size_t o = p;
        p = (p + bytes + 255) & ~(size_t)255;
        return o;
    };
    int*   zeroed  = (int*)(ws + alloc(2048));                   // cnt196 | stats
    int*   cnt196  = zeroed;
    float* stats   = (float*)(zeroed + 256);
    int*   bo      = (int*)(ws + alloc((size_t)(NB + 1) * 4));
    int*   cur     = (int*)(ws + alloc((size_t)NB * 4));
    int*   ebuf    = (int*)(ws + alloc((size_t)NE * 4));         // packed src|ld<<17
    int*   esrc    = (int*)(ws + alloc((size_t)NE * 4));
    int*   off     = (int*)(ws + alloc((size_t)(NN + 1) * 4));
    float* dinv    = (float*)(ws + alloc((size_t)NN * 4));
    __hip_bfloat16* Ah = (__hip_bfloat16*)(ws + alloc((size_t)NN * DD * 2)); // xw bf16
    float* B       = (float*)(ws + alloc((size_t)NN * DD * 4)); // raw agg fp32
    (void)ws_size; (void)in_sizes; (void)n_in; (void)out_size;

    hipMemsetAsync(zeroed, 0, 2048, stream);

    // ---- CSR build, with partition overlapped with layer-1 GEMM ----
    k_hist<<<HIST_BLOCKS, 256, 0, stream>>>(dst, cnt196);
    k_scanb<<<1, 256, 0, stream>>>(cnt196, bo, cur);
    k_pg<<<PART_BLOCKS + GEMM_BLOCKS, 256, 0, stream>>>(x, W1, Ah, src, dst, cur, ebuf);
    k_bucket<<<NB, 512, 0, stream>>>(ebuf, bo, off, dinv, esrc);

    // ---- layer 1 aggregation + stats ----
    k_agg<<<NN / 32, 256, 0, stream>>>(Ah, off, esrc, dinv, B);
    k_stats<<<512, 256, 0, stream>>>(B, stats, NN);

    // ---- layer 2 (BN1+leaky fused into gemm's x-load) ----
    k_gemm2<<<GEMM_BLOCKS, 256, 0, stream>>>(B, W2, Ah, stats, g1, be1);
    k_agg<<<NN / 32, 256, 0, stream>>>(Ah, off, esrc, dinv, B);
    k_stats<<<512, 256, 0, stream>>>(B, stats + 128, NN);
    k_bnact<<<1024, 256, 0, stream>>>(B, out, stats + 128, g2, be2, NN);
}